// Round 5
// baseline (458.247 us; speedup 1.0000x reference)
//
#include <hip/hip_runtime.h>
#include <stdint.h>

// Problem constants (CrossAttentionLayer: B=8, NQ=64, S=4096, D=1024, H=16, HD=64)
#define BATCH   8
#define NQL     64
#define SLEN    4096
#define DMODEL  1024
#define NHEADS  16
#define HDIM    64
#define NSPLIT  8          // S-splits for attention (each split = 512 positions = 8 tiles)

typedef float          f32x4  __attribute__((ext_vector_type(4)));
typedef float          f32x16 __attribute__((ext_vector_type(16)));
typedef __bf16         bf16x8 __attribute__((ext_vector_type(8)));
typedef unsigned int   u32x4  __attribute__((ext_vector_type(4)));
typedef unsigned short u16x4  __attribute__((ext_vector_type(4)));
typedef unsigned short u16x8  __attribute__((ext_vector_type(8)));

__device__ __forceinline__ unsigned short f2bf(float f) {
  unsigned int u = __builtin_bit_cast(unsigned int, f);
  u += 0x7FFFu + ((u >> 16) & 1u);          // RTNE
  return (unsigned short)(u >> 16);
}

__device__ __forceinline__ f32x4 mfma16(bf16x8 a, bf16x8 b, f32x4 c) {
  return __builtin_amdgcn_mfma_f32_16x16x32_bf16(a, b, c, 0, 0, 0);
}

__device__ __forceinline__ bf16x8 lds_frag(const char* p) {
  u32x4 v = *(const u32x4*)p;               // ds_read_b128
  return __builtin_bit_cast(bf16x8, v);
}

__device__ __forceinline__ void gload_lds16(const void* g, void* l) {
  // async global->LDS, 16B per lane; LDS dest = wave-uniform base + lane*16
  __builtin_amdgcn_global_load_lds((const __attribute__((address_space(1))) void*)g,
                                   (__attribute__((address_space(3))) void*)l, 16, 0, 0);
}

// ----------------------------- fp32 -> bf16 convert -----------------------------
__global__ __launch_bounds__(256) void cvt_bf16_kernel(const float* __restrict__ in,
                                                       unsigned short* __restrict__ out,
                                                       int n8) {
  int i = blockIdx.x * 256 + threadIdx.x;
  if (i >= n8) return;
  const float4* p = (const float4*)in + (size_t)i * 2;
  float4 a = p[0], b = p[1];
  u16x8 o;
  o[0] = f2bf(a.x); o[1] = f2bf(a.y); o[2] = f2bf(a.z); o[3] = f2bf(a.w);
  o[4] = f2bf(b.x); o[5] = f2bf(b.y); o[6] = f2bf(b.z); o[7] = f2bf(b.w);
  *((u16x8*)out + i) = o;
}

// ============================ 256x256 pipelined GEMM ============================
// C = A (MxK) * B (NxK)^T + bias.  8 waves (2m x 4n), per-wave 128x64 out,
// mfma_f32_32x32x16_bf16, BK=32, 4-slot LDS ring (128KB), stage kt+3 into slot
// (kt-1)&3.  CROSS-PHASE REGISTER DOUBLE-BUFFER: phase (kt,ks) issues the 6
// ds_read_b128 for the NEXT phase while MFMAing the set loaded LAST phase;
// compiler emits counted lgkmcnt for the true deps -> reads overlap MFMA.
// One s_barrier per phase.  Counted vmcnt chain 6/4/0 at end of phase 0
// guarantees kt+1's stage landed before phase 1 reads slot (kt+1)&3.
// LDS swizzle GF32: byte bits 4-5 ^= row bits 1-2 (involution, both sides).
// MODE 0: bf16 out [M][N].  MODE 2: bf16 transposed V layout
//         Vt[((row>>12)*1024 + col)*4096 + (row&4095)].
#define GF32(a) ((a) ^ ((((a) >> 7) & 3) << 4))

template<int MODE>
__global__ __launch_bounds__(512, 2)
void gemm256(const unsigned short* __restrict__ A, const unsigned short* __restrict__ Bw,
             const float* __restrict__ bias, void* __restrict__ Cout,
             int M, int N, int K) {
  __shared__ char lds[131072];              // 4 ring slots x (A 16KB | B 16KB)

  const int tid = threadIdx.x;
  const int wid = tid >> 6, lane = tid & 63;
  const int l31 = lane & 31, lhi = lane >> 5;
  const int wm = wid >> 2, wn = wid & 3;

  // bijective XCD-chunked swizzle (nwg % 8 == 0 guaranteed by launch)
  const int nbn = N >> 8;
  const int cpx = (int)gridDim.x >> 3;
  const int bid = (int)blockIdx.x;
  const int wg  = (bid & 7) * cpx + (bid >> 3);
  const int brow = (wg / nbn) << 8;
  const int bcol = (wg % nbn) << 8;

  // ---- stage source precompute: dest byte d (linear) -> logical a = GF32(d) ----
  const int aswz = GF32(tid * 16);          // tid*16 in [0,8192)
  const int srow = aswz >> 6;               // logical row 0..127 within call region
  const int skoe = (aswz & 63) >> 1;        // element k-offset 0..31
  const unsigned short* sA0 = A  + (size_t)(brow + srow) * K + skoe;        // A rows 0-127
  const unsigned short* sA1 = A  + (size_t)(brow + 128 + srow) * K + skoe;  // A rows 128-255
  const unsigned short* sB0 = Bw + (size_t)(bcol + srow) * K + skoe;
  const unsigned short* sB1 = Bw + (size_t)(bcol + 128 + srow) * K + skoe;
  const int dd = wid * 1024;                // wave-uniform LDS dest base (HW adds lane*16)

  // ---- read-side fragment byte offsets (constant across kt) ----
  int offA[4][2], offB[2][2];
#pragma unroll
  for (int mi = 0; mi < 4; ++mi)
#pragma unroll
    for (int ks = 0; ks < 2; ++ks) {
      int r = wm * 128 + mi * 32 + l31;
      int a = r * 64 + ks * 32 + lhi * 16;
      offA[mi][ks] = GF32(a);
    }
#pragma unroll
  for (int ni = 0; ni < 2; ++ni)
#pragma unroll
    for (int ks = 0; ks < 2; ++ks) {
      int r = wn * 64 + ni * 32 + l31;
      int a = r * 64 + ks * 32 + lhi * 16;
      offB[ni][ks] = 16384 + GF32(a);
    }

  f32x16 acc[4][2];
#pragma unroll
  for (int mi = 0; mi < 4; ++mi)
#pragma unroll
    for (int ni = 0; ni < 2; ++ni)
#pragma unroll
      for (int e = 0; e < 16; ++e) acc[mi][ni][e] = 0.f;

  auto stageA = [&](int kt, int slot) {     // 2 calls: A rows 0-127, 128-255
    const int ko = kt << 5;
    char* sb = lds + (slot << 15);
    gload_lds16(sA0 + ko, sb + dd);
    gload_lds16(sA1 + ko, sb + 8192 + dd);
  };
  auto stageB = [&](int kt, int slot) {
    const int ko = kt << 5;
    char* sb = lds + (slot << 15) + 16384;
    gload_lds16(sB0 + ko, sb + dd);
    gload_lds16(sB1 + ko, sb + 8192 + dd);
  };

  const int KT = K >> 5;                    // 32
  stageA(0, 0); stageB(0, 0);
  stageA(1, 1); stageB(1, 1);
  stageA(2, 2); stageB(2, 2);
  asm volatile("s_waitcnt vmcnt(8)" ::: "memory");   // kt0's 4 calls retired (in-order)
  __builtin_amdgcn_s_barrier();
  __builtin_amdgcn_sched_barrier(0);

  // prime register set 0 with (kt=0, ks=0)
  bf16x8 af0[4], bf0[2], af1[4], bf1[2];
#pragma unroll
  for (int mi = 0; mi < 4; ++mi) af0[mi] = lds_frag(lds + offA[mi][0]);
#pragma unroll
  for (int ni = 0; ni < 2; ++ni) bf0[ni] = lds_frag(lds + offB[ni][0]);

  for (int kt = 0; kt < KT; ++kt) {
    const char* cur = lds + ((kt & 3) << 15);
    const char* nxt = lds + (((kt + 1) & 3) << 15);
    const int pf = kt + 3;
    const int ps = pf & 3;                  // == (kt-1)&3: freed at kt-1's last barrier

    // ======== phase 0: MFMA set0 (kt,ks0) | load set1 <- (kt,ks1) | stageA(kt+3) ========
#pragma unroll
    for (int mi = 0; mi < 4; ++mi) af1[mi] = lds_frag(cur + offA[mi][1]);
#pragma unroll
    for (int ni = 0; ni < 2; ++ni) bf1[ni] = lds_frag(cur + offB[ni][1]);
    if (pf < KT) stageA(pf, ps);
    __builtin_amdgcn_s_setprio(1);
#pragma unroll
    for (int mi = 0; mi < 4; ++mi)
#pragma unroll
      for (int ni = 0; ni < 2; ++ni)
        acc[mi][ni] = __builtin_amdgcn_mfma_f32_32x32x16_bf16(af0[mi], bf0[ni],
                                                              acc[mi][ni], 0, 0, 0);
    __builtin_amdgcn_s_setprio(0);
    // counted vmcnt chain: after this wait, all of kt+1's stage calls retired;
    // {A,B(kt+2), A(kt+3)} = 6 stay in flight (4/0 near the tail).
    if (kt < KT - 3)       asm volatile("s_waitcnt vmcnt(6)" ::: "memory");
    else if (kt == KT - 3) asm volatile("s_waitcnt vmcnt(4)" ::: "memory");
    else                   asm volatile("s_waitcnt vmcnt(0)" ::: "memory");
    __builtin_amdgcn_s_barrier();
    __builtin_amdgcn_sched_barrier(0);

    // ======== phase 1: MFMA set1 (kt,ks1) | load set0 <- (kt+1,ks0) | stageB(kt+3) ========
    if (kt + 1 < KT) {
#pragma unroll
      for (int mi = 0; mi < 4; ++mi) af0[mi] = lds_frag(nxt + offA[mi][0]);
#pragma unroll
      for (int ni = 0; ni < 2; ++ni) bf0[ni] = lds_frag(nxt + offB[ni][0]);
    }
    if (pf < KT) stageB(pf, ps);
    __builtin_amdgcn_s_setprio(1);
#pragma unroll
    for (int mi = 0; mi < 4; ++mi)
#pragma unroll
      for (int ni = 0; ni < 2; ++ni)
        acc[mi][ni] = __builtin_amdgcn_mfma_f32_32x32x16_bf16(af1[mi], bf1[ni],
                                                              acc[mi][ni], 0, 0, 0);
    __builtin_amdgcn_s_setprio(0);
    __builtin_amdgcn_s_barrier();
    __builtin_amdgcn_sched_barrier(0);
  }

  // ---- epilogue: C/D layout col=lane&31, row=(reg&3)+8*(reg>>2)+4*(lane>>5) ----
#pragma unroll
  for (int mi = 0; mi < 4; ++mi) {
#pragma unroll
    for (int ni = 0; ni < 2; ++ni) {
      f32x16 v = acc[mi][ni];
      const int c = bcol + wn * 64 + ni * 32 + l31;
      const float bi = bias[c];
      const int rbase = brow + wm * 128 + mi * 32 + lhi * 4;
      if constexpr (MODE == 0) {
        unsigned short* Cb = (unsigned short*)Cout;
#pragma unroll
        for (int q = 0; q < 4; ++q)
#pragma unroll
          for (int j = 0; j < 4; ++j)
            Cb[(size_t)(rbase + q * 8 + j) * N + c] = f2bf(v[q * 4 + j] + bi);
      } else {
        unsigned short* Vt = (unsigned short*)Cout;
        const size_t fb = ((size_t)(rbase >> 12) * 1024 + c) * 4096;
#pragma unroll
        for (int q = 0; q < 4; ++q) {
          u16x4 pk;
#pragma unroll
          for (int j = 0; j < 4; ++j) pk[j] = f2bf(v[q * 4 + j] + bi);
          *(u16x4*)(Vt + fb + ((rbase + q * 8) & 4095)) = pk;
        }
      }
    }
  }
}

// ----------------------------- 128x128 GEMM (small M), double-buffered -----------------------------
// MODE 0: bf16 out [M][N].  MODE 1: fp32 out [M][N].
template<int MODE>
__global__ __launch_bounds__(256)
void gemm_bt(const unsigned short* __restrict__ A, const unsigned short* __restrict__ Bw,
             const float* __restrict__ bias, void* __restrict__ Cout,
             int M, int N, int K) {
  __shared__ char lds[65536];               // 2 x (A 16KB | B 16KB)

  const int tid  = threadIdx.x;
  const int wave = tid >> 6, lane = tid & 63;
  const int g    = lane >> 4, ln = lane & 15;
  const int nbn  = N >> 7;
  const int brow = (int)(blockIdx.x / nbn) << 7;
  const int bcol = (int)(blockIdx.x % nbn) << 7;
  const int wr   = wave >> 1, wc = wave & 1;

  f32x4 acc[4][4];
#pragma unroll
  for (int i = 0; i < 4; ++i)
#pragma unroll
    for (int j = 0; j < 4; ++j) acc[i][j] = (f32x4){0.f, 0.f, 0.f, 0.f};

  const int KT = K >> 6;
  const int srow = lane >> 3;
  const int srcs = (lane & 7) ^ (srow & 7);

  auto stage = [&](int kt, char* buf) {
#pragma unroll
    for (int c = wave; c < 16; c += 4) {
      int row = (c << 3) + srow;
      const char* ga = (const char*)A + (((size_t)(brow + row) * K + (kt << 6) + (srcs << 3)) << 1);
      gload_lds16(ga, buf + (c << 10));
      const char* gb = (const char*)Bw + (((size_t)(bcol + row) * K + (kt << 6) + (srcs << 3)) << 1);
      gload_lds16(gb, buf + 16384 + (c << 10));
    }
  };

  stage(0, lds);
  for (int kt = 0; kt < KT; ++kt) {
    char* cur = lds + ((kt & 1) << 15);
    if (kt + 1 < KT) {
      stage(kt + 1, lds + (((kt + 1) & 1) << 15));
      asm volatile("s_waitcnt vmcnt(8)" ::: "memory");   // kt's 8 loads landed
    } else {
      asm volatile("s_waitcnt vmcnt(0)" ::: "memory");
    }
    __builtin_amdgcn_s_barrier();
    __builtin_amdgcn_sched_barrier(0);

#pragma unroll
    for (int ks = 0; ks < 2; ++ks) {
      bf16x8 af[4], bfr[4];
      const int slot = ((ks << 2) + g) ^ (ln & 7);
#pragma unroll
      for (int mt = 0; mt < 4; ++mt) {
        int row = wr * 64 + mt * 16 + ln;
        af[mt] = lds_frag(cur + row * 128 + (slot << 4));
      }
#pragma unroll
      for (int nt = 0; nt < 4; ++nt) {
        int row = wc * 64 + nt * 16 + ln;
        bfr[nt] = lds_frag(cur + 16384 + row * 128 + (slot << 4));
      }
      __builtin_amdgcn_s_setprio(1);
#pragma unroll
      for (int mt = 0; mt < 4; ++mt)
#pragma unroll
        for (int nt = 0; nt < 4; ++nt)
          acc[mt][nt] = mfma16(af[mt], bfr[nt], acc[mt][nt]);
      __builtin_amdgcn_s_setprio(0);
    }
    __builtin_amdgcn_s_barrier();           // all reads of `cur` done before restage
  }

#pragma unroll
  for (int mt = 0; mt < 4; ++mt) {
#pragma unroll
    for (int nt = 0; nt < 4; ++nt) {
      f32x4 v = acc[mt][nt];
      int r0 = brow + wr * 64 + mt * 16 + g * 4;
      int c  = bcol + wc * 64 + nt * 16 + ln;
      float bi = bias[c];
      if constexpr (MODE == 0) {
        unsigned short* Cb = (unsigned short*)Cout;
#pragma unroll
        for (int j = 0; j < 4; ++j) Cb[(size_t)(r0 + j) * N + c] = f2bf(v[j] + bi);
      } else {
        float* Cf = (float*)Cout;
#pragma unroll
        for (int j = 0; j < 4; ++j) Cf[(size_t)(r0 + j) * N + c] = v[j] + bi;
      }
    }
  }
}

// ----------------------------- split-S fused flash attention -----------------------------
// grid = B*H*NSPLIT.  block = bh*NSPLIT + sp.  Each block: 64 q rows x 512 s positions
// (8 tiles of 64).  Emits UNNORMALIZED partial O (f32) + per-row m,l for combine.
__global__ __launch_bounds__(256)
void attn_split(const unsigned short* __restrict__ Qp,  // [B*NQ][1024]
                const unsigned short* __restrict__ Kp,  // [B*S][1024]
                const unsigned short* __restrict__ Vt,  // [b*1024 + h*64 + hd][4096]
                float* __restrict__ Opart,              // [(sp*128+bh)*64 + q][64]
                float* __restrict__ Mpart,              // [(sp*128+bh)*64 + q]
                float* __restrict__ Lpart) {
  __shared__ char ldsKV[2][16384];                       // [buf][ K 8KB | V 8KB ]
  __shared__ unsigned int plds[4 * 16 * 36];

  const int bh = (int)blockIdx.x / NSPLIT;
  const int sp = (int)blockIdx.x % NSPLIT;
  const int b = bh >> 4, h = bh & 15;
  const int tid = threadIdx.x;
  const int wave = tid >> 6, lane = tid & 63;
  const int g = lane >> 4, ln = lane & 15;
  const int pbase = wave * 576 + ln * 36;
  const int srow = lane >> 3;
  const int srcs = (lane & 7) ^ (srow & 7);

  const unsigned short* qb =
      Qp + ((size_t)(b * 64 + wave * 16 + ln) * 1024) + h * 64 + g * 8;
  bf16x8 qf[2];
  qf[0] = __builtin_bit_cast(bf16x8, *(const u32x4*)qb);
  qf[1] = __builtin_bit_cast(bf16x8, *(const u32x4*)(qb + 32));

  f32x4 oacc[4];
#pragma unroll
  for (int i = 0; i < 4; ++i) oacc[i] = (f32x4){0.f, 0.f, 0.f, 0.f};
  float mrun = -1e30f, lrun = 0.f;

  auto stage = [&](int t, int buf) {        // t = GLOBAL tile index (0..63)
    int s0 = t << 6;
    char* bK = ldsKV[buf];
#pragma unroll
    for (int c4 = 0; c4 < 4; ++c4) {
      int c = wave * 4 + c4;
      int cc = c & 7;
      int row = (cc << 3) + srow;
      const char* gsrc;
      if (c < 8)
        gsrc = (const char*)Kp + (((size_t)((b << 12) + s0 + row) * 1024 + (h << 6) + (srcs << 3)) << 1);
      else
        gsrc = (const char*)Vt + (((size_t)((b << 10) + (h << 6) + row) * 4096 + s0 + (srcs << 3)) << 1);
      gload_lds16(gsrc, bK + ((c < 8) ? 0 : 8192) + (cc << 10));
    }
  };

  const int T0 = sp * (SLEN / 64 / NSPLIT);              // 8 tiles per split
  const int NTL = SLEN / 64 / NSPLIT;
  stage(T0, 0);
  for (int tl = 0; tl < NTL; ++tl) {
    asm volatile("s_waitcnt vmcnt(0)" ::: "memory");
    __syncthreads();
    if (tl + 1 < NTL) stage(T0 + tl + 1, (tl + 1) & 1);

    char* bufK = ldsKV[tl & 1];
    char* bufV = bufK + 8192;

    f32x4 s4[4];
#pragma unroll
    for (int i = 0; i < 4; ++i) s4[i] = (f32x4){0.f, 0.f, 0.f, 0.f};
    __builtin_amdgcn_s_setprio(1);
#pragma unroll
    for (int ks = 0; ks < 2; ++ks) {
      const int slot = ((ks << 2) + g) ^ (ln & 7);
#pragma unroll
      for (int mt = 0; mt < 4; ++mt) {
        int row = mt * 16 + ln;
        s4[mt] = mfma16(lds_frag(bufK + row * 128 + (slot << 4)), qf[ks], s4[mt]);
      }
    }
    __builtin_amdgcn_s_setprio(0);

    float tmax = -1e30f;
#pragma unroll
    for (int mt = 0; mt < 4; ++mt)
#pragma unroll
      for (int j = 0; j < 4; ++j) {
        float sv = s4[mt][j] * 0.125f;
        s4[mt][j] = sv;
        tmax = fmaxf(tmax, sv);
      }
    tmax = fmaxf(tmax, __shfl_xor(tmax, 16));
    tmax = fmaxf(tmax, __shfl_xor(tmax, 32));
    float mnew = fmaxf(mrun, tmax);
    float factor = __expf(mrun - mnew);
    float psum = 0.f;
#pragma unroll
    for (int mt = 0; mt < 4; ++mt) {
      float p0 = __expf(s4[mt][0] - mnew);
      float p1 = __expf(s4[mt][1] - mnew);
      float p2 = __expf(s4[mt][2] - mnew);
      float p3 = __expf(s4[mt][3] - mnew);
      psum += (p0 + p1) + (p2 + p3);
      plds[pbase + mt * 8 + g * 2 + 0] = (unsigned)f2bf(p0) | ((unsigned)f2bf(p1) << 16);
      plds[pbase + mt * 8 + g * 2 + 1] = (unsigned)f2bf(p2) | ((unsigned)f2bf(p3) << 16);
    }
    psum += __shfl_xor(psum, 16);
    psum += __shfl_xor(psum, 32);
    lrun = lrun * factor + psum;
    mrun = mnew;

    float fj0 = __shfl(factor, g * 4 + 0);
    float fj1 = __shfl(factor, g * 4 + 1);
    float fj2 = __shfl(factor, g * 4 + 2);
    float fj3 = __shfl(factor, g * 4 + 3);
#pragma unroll
    for (int nt = 0; nt < 4; ++nt) {
      oacc[nt][0] *= fj0; oacc[nt][1] *= fj1; oacc[nt][2] *= fj2; oacc[nt][3] *= fj3;
    }

    __builtin_amdgcn_s_setprio(1);
#pragma unroll
    for (int kt2 = 0; kt2 < 2; ++kt2) {
      u32x4 pv;
      int pidx = pbase + kt2 * 16 + g * 4;
      pv[0] = plds[pidx]; pv[1] = plds[pidx + 1]; pv[2] = plds[pidx + 2]; pv[3] = plds[pidx + 3];
      bf16x8 pa = __builtin_bit_cast(bf16x8, pv);
      const int slot = ((kt2 << 2) + g) ^ (ln & 7);
#pragma unroll
      for (int nt = 0; nt < 4; ++nt) {
        int row = nt * 16 + ln;
        oacc[nt] = mfma16(pa, lds_frag(bufV + row * 128 + (slot << 4)), oacc[nt]);
      }
    }
    __builtin_amdgcn_s_setprio(0);
  }

  // epilogue: store UNNORMALIZED partial O + m,l
  const int rowb = sp * (BATCH * NHEADS * 64) + bh * 64;   // sp*8192 + bh*64
#pragma unroll
  for (int nt = 0; nt < 4; ++nt) {
#pragma unroll
    for (int j = 0; j < 4; ++j) {
      int q = wave * 16 + g * 4 + j;
      Opart[(size_t)(rowb + q) * 64 + nt * 16 + ln] = oacc[nt][j];
    }
  }
  if (g == 0) {
    Mpart[rowb + wave * 16 + ln] = mrun;
    Lpart[rowb + wave * 16 + ln] = lrun;
  }
}

// ----------------------------- split combine -----------------------------
__global__ __launch_bounds__(256)
void attn_combine(const float* __restrict__ Opart, const float* __restrict__ Mpart,
                  const float* __restrict__ Lpart, unsigned short* __restrict__ Aout) {
  const int blk = blockIdx.x;               // 2048 = 128 bh x 16 q-quads
  const int bh = blk >> 4;
  const int q  = ((blk & 15) << 2) + (threadIdx.x >> 6);
  const int hd = threadIdx.x & 63;
  const int row = bh * 64 + q;              // 0..8191

  float mi[NSPLIT];
  float M = -1e30f;
#pragma unroll
  for (int i = 0; i < NSPLIT; ++i) {
    mi[i] = Mpart[i * 8192 + row];
    M = fmaxf(M, mi[i]);
  }
  float L = 0.f, o = 0.f;
#pragma unroll
  for (int i = 0; i < NSPLIT; ++i) {
    float w = __expf(mi[i] - M);
    L += Lpart[i * 8192 + row] * w;
    o += Opart[(size_t)(i * 8192 + row) * 64 + hd] * w;
  }
  const int b = bh >> 4, h = bh & 15;
  Aout[(size_t)(b * 64 + q) * 1024 + h * 64 + hd] = f2bf(o / L);
}

// ----------------------------- launch -----------------------------
extern "C" void kernel_launch(void* const* d_in, const int* in_sizes, int n_in,
                              void* d_out, int out_size, void* d_ws, size_t ws_size,
                              hipStream_t stream) {
  const float* queries = (const float*)d_in[0];
  const float* context = (const float*)d_in[1];
  const float* wq = (const float*)d_in[2];
  const float* bq = (const float*)d_in[3];
  const float* wk = (const float*)d_in[4];
  const float* bk = (const float*)d_in[5];
  const float* wv = (const float*)d_in[6];
  const float* bv = (const float*)d_in[7];
  const float* wo = (const float*)d_in[8];
  const float* bo = (const float*)d_in[9];

  const size_t CTX_E = (size_t)BATCH * SLEN * DMODEL;   // 33,554,432
  const size_t QRY_E = (size_t)BATCH * NQL * DMODEL;    // 524,288
  const size_t W_E   = (size_t)DMODEL * DMODEL;         // 1,048,576

  char* ws = (char*)d_ws;
  size_t off = 0;
  auto alloc = [&](size_t bytes) {
    char* p = ws + off;
    off += (bytes + 255) & ~(size_t)255;
    return p;
  };
  unsigned short* ctx_bf = (unsigned short*)alloc(CTX_E * 2);
  unsigned short* q_bf   = (unsigned short*)alloc(QRY_E * 2);
  unsigned short* wq_bf  = (unsigned short*)alloc(W_E * 2);
  unsigned short* wk_bf  = (unsigned short*)alloc(W_E * 2);
  unsigned short* wv_bf  = (unsigned short*)alloc(W_E * 2);
  unsigned short* wo_bf  = (unsigned short*)alloc(W_E * 2);
  unsigned short* Qp     = (unsigned short*)alloc(QRY_E * 2);
  unsigned short* Kp     = (unsigned short*)alloc(CTX_E * 2);
  unsigned short* Vt     = (unsigned short*)alloc(CTX_E * 2);
  unsigned short* Ao     = (unsigned short*)alloc(QRY_E * 2);
  if (off > ws_size) return;

  // attention partials ALIAS ctx_bf (dead after the V-projection GEMM):
  // Opart 16.78MB + Mpart 256KB + Lpart 256KB  <  67MB
  float* Opart = (float*)ctx_bf;
  float* Mpart = Opart + (size_t)NSPLIT * BATCH * NHEADS * 64 * 64;
  float* Lpart = Mpart + (size_t)NSPLIT * BATCH * NHEADS * 64;

  cvt_bf16_kernel<<<dim3((int)(CTX_E / 8 / 256)), 256, 0, stream>>>(context, ctx_bf, (int)(CTX_E / 8));
  cvt_bf16_kernel<<<dim3((int)(QRY_E / 8 / 256)), 256, 0, stream>>>(queries, q_bf, (int)(QRY_E / 8));
  cvt_bf16_kernel<<<dim3((int)(W_E / 8 / 256)), 256, 0, stream>>>(wq, wq_bf, (int)(W_E / 8));
  cvt_bf16_kernel<<<dim3((int)(W_E / 8 / 256)), 256, 0, stream>>>(wk, wk_bf, (int)(W_E / 8));
  cvt_bf16_kernel<<<dim3((int)(W_E / 8 / 256)), 256, 0, stream>>>(wv, wv_bf, (int)(W_E / 8));
  cvt_bf16_kernel<<<dim3((int)(W_E / 8 / 256)), 256, 0, stream>>>(wo, wo_bf, (int)(W_E / 8));

  const int M_KV = BATCH * SLEN;  // 32768
  const int M_Q  = BATCH * NQL;   // 512

  gemm256<0><<<dim3((M_KV / 256) * (DMODEL / 256)), 512, 0, stream>>>(ctx_bf, wk_bf, bk, Kp, M_KV, DMODEL, DMODEL);
  gemm256<2><<<dim3((M_KV / 256) * (DMODEL / 256)), 512, 0, stream>>>(ctx_bf, wv_bf, bv, Vt, M_KV, DMODEL, DMODEL);

  gemm_bt<0><<<dim3((M_Q / 128) * (DMODEL / 128)), 256, 0, stream>>>(q_bf, wq_bf, bq, Qp, M_Q, DMODEL, DMODEL);

  attn_split<<<dim3(BATCH * NHEADS * NSPLIT), 256, 0, stream>>>(Qp, Kp, Vt, Opart, Mpart, Lpart);
  attn_combine<<<dim3(BATCH * NHEADS * 16), 256, 0, stream>>>(Opart, Mpart, Lpart, Ao);

  gemm_bt<1><<<dim3((M_Q / 128) * (DMODEL / 128)), 256, 0, stream>>>(Ao, wo_bf, bo, d_out, M_Q, DMODEL, DMODEL);
}

// Round 6
// 435.667 us; speedup vs baseline: 1.0518x; 1.0518x over previous
//
#include <hip/hip_runtime.h>
#include <stdint.h>

// Problem constants (CrossAttentionLayer: B=8, NQ=64, S=4096, D=1024, H=16, HD=64)
#define BATCH   8
#define NQL     64
#define SLEN    4096
#define DMODEL  1024
#define NHEADS  16
#define HDIM    64
#define NSPLIT  8          // S-splits for attention (each split = 512 positions = 8 tiles)

typedef float          f32x4  __attribute__((ext_vector_type(4)));
typedef __bf16         bf16x8 __attribute__((ext_vector_type(8)));
typedef unsigned int   u32x4  __attribute__((ext_vector_type(4)));
typedef unsigned short u16x4  __attribute__((ext_vector_type(4)));
typedef unsigned short u16x8  __attribute__((ext_vector_type(8)));

__device__ __forceinline__ unsigned short f2bf(float f) {
  unsigned int u = __builtin_bit_cast(unsigned int, f);
  u += 0x7FFFu + ((u >> 16) & 1u);          // RTNE
  return (unsigned short)(u >> 16);
}

__device__ __forceinline__ f32x4 mfma16(bf16x8 a, bf16x8 b, f32x4 c) {
  return __builtin_amdgcn_mfma_f32_16x16x32_bf16(a, b, c, 0, 0, 0);
}

__device__ __forceinline__ bf16x8 lds_frag(const char* p) {
  u32x4 v = *(const u32x4*)p;               // ds_read_b128
  return __builtin_bit_cast(bf16x8, v);
}

__device__ __forceinline__ void gload_lds16(const void* g, void* l) {
  // async global->LDS, 16B per lane; LDS dest = wave-uniform base + lane*16
  __builtin_amdgcn_global_load_lds((const __attribute__((address_space(1))) void*)g,
                                   (__attribute__((address_space(3))) void*)l, 16, 0, 0);
}

// ----------------------------- fused fp32 -> bf16 convert (6 segments, 1 launch) --------------
// segment prefix sums in n8 units:
//   ctx 4194304 | q 65536 | wq/wk/wv/wo 131072 each ; total 4784128 (= 18688 * 256)
__global__ __launch_bounds__(256)
void cvt6_kernel(const float* __restrict__ p0, const float* __restrict__ p1,
                 const float* __restrict__ p2, const float* __restrict__ p3,
                 const float* __restrict__ p4, const float* __restrict__ p5,
                 unsigned short* __restrict__ o0, unsigned short* __restrict__ o1,
                 unsigned short* __restrict__ o2, unsigned short* __restrict__ o3,
                 unsigned short* __restrict__ o4, unsigned short* __restrict__ o5) {
  int i = blockIdx.x * 256 + threadIdx.x;
  const float* src; unsigned short* dst; int rel;
  if      (i < 4194304) { src = p0; dst = o0; rel = i; }
  else if (i < 4259840) { src = p1; dst = o1; rel = i - 4194304; }
  else if (i < 4390912) { src = p2; dst = o2; rel = i - 4259840; }
  else if (i < 4521984) { src = p3; dst = o3; rel = i - 4390912; }
  else if (i < 4653056) { src = p4; dst = o4; rel = i - 4521984; }
  else                  { src = p5; dst = o5; rel = i - 4653056; }
  const float4* p = (const float4*)src + (size_t)rel * 2;
  float4 a = p[0], b = p[1];
  u16x8 o;
  o[0] = f2bf(a.x); o[1] = f2bf(a.y); o[2] = f2bf(a.z); o[3] = f2bf(a.w);
  o[4] = f2bf(b.x); o[5] = f2bf(b.y); o[6] = f2bf(b.z); o[7] = f2bf(b.w);
  *((u16x8*)dst + rel) = o;
}

// ----------------------------- 128x128 GEMM, dbuf, XCD-chunked ------------------------------
// C = A (MxK) * B (NxK)^T + bias.  4 waves (2x2), per-wave 64x64, 16x16x32 MFMA,
// BK=64, double-buffered 64KB LDS (-> 2 blocks/CU: cross-block overlap fills the
// barrier/drain windows), counted vmcnt(8).  XCD-chunked wg swizzle: all 8
// column-blocks of one A row-panel land on the SAME XCD -> A fetched once into L2
// (fixes R1's 4x over-fetch).  Read swizzle slot^(ln&7): measured 0 conflicts.
// MODE 0: bf16 out [M][N].  MODE 1: fp32 out [M][N].  MODE 2: bf16 transposed V
//         layout Vt[((r>>12)*1024 + c)*4096 + (r&4095)].
template<int MODE>
__global__ __launch_bounds__(256)
void gemm_bt(const unsigned short* __restrict__ A, const unsigned short* __restrict__ Bw,
             const float* __restrict__ bias, void* __restrict__ Cout,
             int M, int N, int K) {
  __shared__ char lds[65536];               // 2 x (A 16KB | B 16KB)

  const int tid  = threadIdx.x;
  const int wave = tid >> 6, lane = tid & 63;
  const int g    = lane >> 4, ln = lane & 15;

  // XCD-chunked bijective swizzle (nwg % 8 == 0 guaranteed by launch)
  const int nwg = (int)gridDim.x;
  const int cpx = nwg >> 3;
  const int bid = (int)blockIdx.x;
  const int wg  = (bid & 7) * cpx + (bid >> 3);
  const int nbn  = N >> 7;
  const int brow = (wg / nbn) << 7;
  const int bcol = (wg % nbn) << 7;
  const int wr   = wave >> 1, wc = wave & 1;

  f32x4 acc[4][4];
#pragma unroll
  for (int i = 0; i < 4; ++i)
#pragma unroll
    for (int j = 0; j < 4; ++j) acc[i][j] = (f32x4){0.f, 0.f, 0.f, 0.f};

  const int KT = K >> 6;
  const int srow = lane >> 3;
  const int srcs = (lane & 7) ^ (srow & 7);

  auto stage = [&](int kt, char* buf) {
#pragma unroll
    for (int c = wave; c < 16; c += 4) {
      int row = (c << 3) + srow;
      const char* ga = (const char*)A + (((size_t)(brow + row) * K + (kt << 6) + (srcs << 3)) << 1);
      gload_lds16(ga, buf + (c << 10));
      const char* gb = (const char*)Bw + (((size_t)(bcol + row) * K + (kt << 6) + (srcs << 3)) << 1);
      gload_lds16(gb, buf + 16384 + (c << 10));
    }
  };

  stage(0, lds);
  for (int kt = 0; kt < KT; ++kt) {
    char* cur = lds + ((kt & 1) << 15);
    if (kt + 1 < KT) {
      stage(kt + 1, lds + (((kt + 1) & 1) << 15));
      asm volatile("s_waitcnt vmcnt(8)" ::: "memory");   // kt's 8 loads landed; kt+1's fly on
    } else {
      asm volatile("s_waitcnt vmcnt(0)" ::: "memory");
    }
    __builtin_amdgcn_s_barrier();
    __builtin_amdgcn_sched_barrier(0);

#pragma unroll
    for (int ks = 0; ks < 2; ++ks) {
      bf16x8 af[4], bfr[4];
      const int slot = ((ks << 2) + g) ^ (ln & 7);
#pragma unroll
      for (int mt = 0; mt < 4; ++mt) {
        int row = wr * 64 + mt * 16 + ln;
        af[mt] = lds_frag(cur + row * 128 + (slot << 4));
      }
#pragma unroll
      for (int nt = 0; nt < 4; ++nt) {
        int row = wc * 64 + nt * 16 + ln;
        bfr[nt] = lds_frag(cur + 16384 + row * 128 + (slot << 4));
      }
      __builtin_amdgcn_s_setprio(1);
#pragma unroll
      for (int mt = 0; mt < 4; ++mt)
#pragma unroll
        for (int nt = 0; nt < 4; ++nt)
          acc[mt][nt] = mfma16(af[mt], bfr[nt], acc[mt][nt]);
      __builtin_amdgcn_s_setprio(0);
    }
    __builtin_amdgcn_s_barrier();           // all reads of `cur` done before restage
  }

#pragma unroll
  for (int mt = 0; mt < 4; ++mt) {
#pragma unroll
    for (int nt = 0; nt < 4; ++nt) {
      f32x4 v = acc[mt][nt];
      int r0 = brow + wr * 64 + mt * 16 + g * 4;
      int c  = bcol + wc * 64 + nt * 16 + ln;
      float bi = bias[c];
      if constexpr (MODE == 0) {
        unsigned short* Cb = (unsigned short*)Cout;
#pragma unroll
        for (int j = 0; j < 4; ++j) Cb[(size_t)(r0 + j) * N + c] = f2bf(v[j] + bi);
      } else if constexpr (MODE == 1) {
        float* Cf = (float*)Cout;
#pragma unroll
        for (int j = 0; j < 4; ++j) Cf[(size_t)(r0 + j) * N + c] = v[j] + bi;
      } else {
        u16x4 pk;
#pragma unroll
        for (int j = 0; j < 4; ++j) pk[j] = f2bf(v[j] + bi);
        size_t base = ((size_t)(r0 >> 12) * 1024 + c) * 4096 + (size_t)(r0 & 4095);
        *(u16x4*)((unsigned short*)Cout + base) = pk;
      }
    }
  }
}

// ----------------------------- split-S fused flash attention -----------------------------
// grid = B*H*NSPLIT.  block = bh*NSPLIT + sp.  Each block: 64 q rows x 512 s positions
// (8 tiles of 64).  Emits UNNORMALIZED partial O (f32) + per-row m,l for combine.
__global__ __launch_bounds__(256)
void attn_split(const unsigned short* __restrict__ Qp,  // [B*NQ][1024]
                const unsigned short* __restrict__ Kp,  // [B*S][1024]
                const unsigned short* __restrict__ Vt,  // [b*1024 + h*64 + hd][4096]
                float* __restrict__ Opart,              // [(sp*128+bh)*64 + q][64]
                float* __restrict__ Mpart,              // [(sp*128+bh)*64 + q]
                float* __restrict__ Lpart) {
  __shared__ char ldsKV[2][16384];                       // [buf][ K 8KB | V 8KB ]
  __shared__ unsigned int plds[4 * 16 * 36];

  const int bh = (int)blockIdx.x / NSPLIT;
  const int sp = (int)blockIdx.x % NSPLIT;
  const int b = bh >> 4, h = bh & 15;
  const int tid = threadIdx.x;
  const int wave = tid >> 6, lane = tid & 63;
  const int g = lane >> 4, ln = lane & 15;
  const int pbase = wave * 576 + ln * 36;
  const int srow = lane >> 3;
  const int srcs = (lane & 7) ^ (srow & 7);

  const unsigned short* qb =
      Qp + ((size_t)(b * 64 + wave * 16 + ln) * 1024) + h * 64 + g * 8;
  bf16x8 qf[2];
  qf[0] = __builtin_bit_cast(bf16x8, *(const u32x4*)qb);
  qf[1] = __builtin_bit_cast(bf16x8, *(const u32x4*)(qb + 32));

  f32x4 oacc[4];
#pragma unroll
  for (int i = 0; i < 4; ++i) oacc[i] = (f32x4){0.f, 0.f, 0.f, 0.f};
  float mrun = -1e30f, lrun = 0.f;

  auto stage = [&](int t, int buf) {        // t = GLOBAL tile index (0..63)
    int s0 = t << 6;
    char* bK = ldsKV[buf];
#pragma unroll
    for (int c4 = 0; c4 < 4; ++c4) {
      int c = wave * 4 + c4;
      int cc = c & 7;
      int row = (cc << 3) + srow;
      const char* gsrc;
      if (c < 8)
        gsrc = (const char*)Kp + (((size_t)((b << 12) + s0 + row) * 1024 + (h << 6) + (srcs << 3)) << 1);
      else
        gsrc = (const char*)Vt + (((size_t)((b << 10) + (h << 6) + row) * 4096 + s0 + (srcs << 3)) << 1);
      gload_lds16(gsrc, bK + ((c < 8) ? 0 : 8192) + (cc << 10));
    }
  };

  const int T0 = sp * (SLEN / 64 / NSPLIT);              // 8 tiles per split
  const int NTL = SLEN / 64 / NSPLIT;
  stage(T0, 0);
  for (int tl = 0; tl < NTL; ++tl) {
    asm volatile("s_waitcnt vmcnt(0)" ::: "memory");
    __syncthreads();
    if (tl + 1 < NTL) stage(T0 + tl + 1, (tl + 1) & 1);

    char* bufK = ldsKV[tl & 1];
    char* bufV = bufK + 8192;

    f32x4 s4[4];
#pragma unroll
    for (int i = 0; i < 4; ++i) s4[i] = (f32x4){0.f, 0.f, 0.f, 0.f};
    __builtin_amdgcn_s_setprio(1);
#pragma unroll
    for (int ks = 0; ks < 2; ++ks) {
      const int slot = ((ks << 2) + g) ^ (ln & 7);
#pragma unroll
      for (int mt = 0; mt < 4; ++mt) {
        int row = mt * 16 + ln;
        s4[mt] = mfma16(lds_frag(bufK + row * 128 + (slot << 4)), qf[ks], s4[mt]);
      }
    }
    __builtin_amdgcn_s_setprio(0);

    float tmax = -1e30f;
#pragma unroll
    for (int mt = 0; mt < 4; ++mt)
#pragma unroll
      for (int j = 0; j < 4; ++j) {
        float sv = s4[mt][j] * 0.125f;
        s4[mt][j] = sv;
        tmax = fmaxf(tmax, sv);
      }
    tmax = fmaxf(tmax, __shfl_xor(tmax, 16));
    tmax = fmaxf(tmax, __shfl_xor(tmax, 32));
    float mnew = fmaxf(mrun, tmax);
    float factor = __expf(mrun - mnew);
    float psum = 0.f;
#pragma unroll
    for (int mt = 0; mt < 4; ++mt) {
      float p0 = __expf(s4[mt][0] - mnew);
      float p1 = __expf(s4[mt][1] - mnew);
      float p2 = __expf(s4[mt][2] - mnew);
      float p3 = __expf(s4[mt][3] - mnew);
      psum += (p0 + p1) + (p2 + p3);
      plds[pbase + mt * 8 + g * 2 + 0] = (unsigned)f2bf(p0) | ((unsigned)f2bf(p1) << 16);
      plds[pbase + mt * 8 + g * 2 + 1] = (unsigned)f2bf(p2) | ((unsigned)f2bf(p3) << 16);
    }
    psum += __shfl_xor(psum, 16);
    psum += __shfl_xor(psum, 32);
    lrun = lrun * factor + psum;
    mrun = mnew;

    float fj0 = __shfl(factor, g * 4 + 0);
    float fj1 = __shfl(factor, g * 4 + 1);
    float fj2 = __shfl(factor, g * 4 + 2);
    float fj3 = __shfl(factor, g * 4 + 3);
#pragma unroll
    for (int nt = 0; nt < 4; ++nt) {
      oacc[nt][0] *= fj0; oacc[nt][1] *= fj1; oacc[nt][2] *= fj2; oacc[nt][3] *= fj3;
    }

    __builtin_amdgcn_s_setprio(1);
#pragma unroll
    for (int kt2 = 0; kt2 < 2; ++kt2) {
      u32x4 pv;
      int pidx = pbase + kt2 * 16 + g * 4;
      pv[0] = plds[pidx]; pv[1] = plds[pidx + 1]; pv[2] = plds[pidx + 2]; pv[3] = plds[pidx + 3];
      bf16x8 pa = __builtin_bit_cast(bf16x8, pv);
      const int slot = ((kt2 << 2) + g) ^ (ln & 7);
#pragma unroll
      for (int nt = 0; nt < 4; ++nt) {
        int row = nt * 16 + ln;
        oacc[nt] = mfma16(pa, lds_frag(bufV + row * 128 + (slot << 4)), oacc[nt]);
      }
    }
    __builtin_amdgcn_s_setprio(0);
  }

  // epilogue: store UNNORMALIZED partial O + m,l
  const int rowb = sp * (BATCH * NHEADS * 64) + bh * 64;   // sp*8192 + bh*64
#pragma unroll
  for (int nt = 0; nt < 4; ++nt) {
#pragma unroll
    for (int j = 0; j < 4; ++j) {
      int q = wave * 16 + g * 4 + j;
      Opart[(size_t)(rowb + q) * 64 + nt * 16 + ln] = oacc[nt][j];
    }
  }
  if (g == 0) {
    Mpart[rowb + wave * 16 + ln] = mrun;
    Lpart[rowb + wave * 16 + ln] = lrun;
  }
}

// ----------------------------- split combine -----------------------------
__global__ __launch_bounds__(256)
void attn_combine(const float* __restrict__ Opart, const float* __restrict__ Mpart,
                  const float* __restrict__ Lpart, unsigned short* __restrict__ Aout) {
  const int blk = blockIdx.x;               // 2048 = 128 bh x 16 q-quads
  const int bh = blk >> 4;
  const int q  = ((blk & 15) << 2) + (threadIdx.x >> 6);
  const int hd = threadIdx.x & 63;
  const int row = bh * 64 + q;              // 0..8191

  float mi[NSPLIT];
  float M = -1e30f;
#pragma unroll
  for (int i = 0; i < NSPLIT; ++i) {
    mi[i] = Mpart[i * 8192 + row];
    M = fmaxf(M, mi[i]);
  }
  float L = 0.f, o = 0.f;
#pragma unroll
  for (int i = 0; i < NSPLIT; ++i) {
    float w = __expf(mi[i] - M);
    L += Lpart[i * 8192 + row] * w;
    o += Opart[(size_t)(i * 8192 + row) * 64 + hd] * w;
  }
  const int b = bh >> 4, h = bh & 15;
  Aout[(size_t)(b * 64 + q) * 1024 + h * 64 + hd] = f2bf(o / L);
}

// ----------------------------- launch -----------------------------
extern "C" void kernel_launch(void* const* d_in, const int* in_sizes, int n_in,
                              void* d_out, int out_size, void* d_ws, size_t ws_size,
                              hipStream_t stream) {
  const float* queries = (const float*)d_in[0];
  const float* context = (const float*)d_in[1];
  const float* wq = (const float*)d_in[2];
  const float* bq = (const float*)d_in[3];
  const float* wk = (const float*)d_in[4];
  const float* bk = (const float*)d_in[5];
  const float* wv = (const float*)d_in[6];
  const float* bv = (const float*)d_in[7];
  const float* wo = (const float*)d_in[8];
  const float* bo = (const float*)d_in[9];

  const size_t CTX_E = (size_t)BATCH * SLEN * DMODEL;   // 33,554,432
  const size_t QRY_E = (size_t)BATCH * NQL * DMODEL;    // 524,288
  const size_t W_E   = (size_t)DMODEL * DMODEL;         // 1,048,576

  char* ws = (char*)d_ws;
  size_t off = 0;
  auto alloc = [&](size_t bytes) {
    char* p = ws + off;
    off += (bytes + 255) & ~(size_t)255;
    return p;
  };
  unsigned short* ctx_bf = (unsigned short*)alloc(CTX_E * 2);
  unsigned short* q_bf   = (unsigned short*)alloc(QRY_E * 2);
  unsigned short* wq_bf  = (unsigned short*)alloc(W_E * 2);
  unsigned short* wk_bf  = (unsigned short*)alloc(W_E * 2);
  unsigned short* wv_bf  = (unsigned short*)alloc(W_E * 2);
  unsigned short* wo_bf  = (unsigned short*)alloc(W_E * 2);
  unsigned short* Qp     = (unsigned short*)alloc(QRY_E * 2);
  unsigned short* Kp     = (unsigned short*)alloc(CTX_E * 2);
  unsigned short* Vt     = (unsigned short*)alloc(CTX_E * 2);
  unsigned short* Ao     = (unsigned short*)alloc(QRY_E * 2);
  if (off > ws_size) return;

  // attention partials ALIAS ctx_bf (dead after the V-projection GEMM):
  // Opart 16.78MB + Mpart 256KB + Lpart 256KB  <  67MB
  float* Opart = (float*)ctx_bf;
  float* Mpart = Opart + (size_t)NSPLIT * BATCH * NHEADS * 64 * 64;
  float* Lpart = Mpart + (size_t)NSPLIT * BATCH * NHEADS * 64;

  // fused convert: 6 segments, one launch (18688 blocks exactly)
  cvt6_kernel<<<dim3(18688), 256, 0, stream>>>(context, queries, wq, wk, wv, wo,
                                               ctx_bf, q_bf, wq_bf, wk_bf, wv_bf, wo_bf);

  const int M_KV = BATCH * SLEN;  // 32768
  const int M_Q  = BATCH * NQL;   // 512

  // big projections: 128^2 dbuf GEMM, 2 blocks/CU, XCD-chunked (grid 2048 % 8 == 0)
  gemm_bt<0><<<dim3((M_KV / 128) * (DMODEL / 128)), 256, 0, stream>>>(ctx_bf, wk_bf, bk, Kp, M_KV, DMODEL, DMODEL);
  gemm_bt<2><<<dim3((M_KV / 128) * (DMODEL / 128)), 256, 0, stream>>>(ctx_bf, wv_bf, bv, Vt, M_KV, DMODEL, DMODEL);

  gemm_bt<0><<<dim3((M_Q / 128) * (DMODEL / 128)), 256, 0, stream>>>(q_bf, wq_bf, bq, Qp, M_Q, DMODEL, DMODEL);

  attn_split<<<dim3(BATCH * NHEADS * NSPLIT), 256, 0, stream>>>(Qp, Kp, Vt, Opart, Mpart, Lpart);
  attn_combine<<<dim3(BATCH * NHEADS * 16), 256, 0, stream>>>(Opart, Mpart, Lpart, Ao);

  gemm_bt<1><<<dim3((M_Q / 128) * (DMODEL / 128)), 256, 0, stream>>>(Ao, wo_bf, bo, d_out, M_Q, DMODEL, DMODEL);
}